// Round 1
// baseline (102.840 us; speedup 1.0000x reference)
//
#include <hip/hip_runtime.h>

// GraphAttention: x[2,512,512], adj[2,512,512], 3x proj W[512,512]+b, aff[16,32],
// aff_bias[16] (softmax-invariant, skipped), ln_g/ln_b[512].
// Pipeline: conv(f32->bf16) -> proj (bf16 MFMA, f32 out) -> aux (sa/sb matvecs)
//        -> attn (VALU pairwise scores + online softmax + PV, flash combine)
//        -> layernorm+relu.
// lrelu(x,0.2) == 0.6x + 0.4|x| exactly -> scores = 0.6(sa_i+sb_j) + 0.4*sum aff*|A+B|.

#define NB 2
#define NN 512
#define DM 512
#define NH 16
#define DD 32

typedef __attribute__((ext_vector_type(8))) short bf16x8;
typedef __attribute__((ext_vector_type(4))) float f32x4;

__device__ __forceinline__ unsigned short f2bf(float f) {
  unsigned int u = __float_as_uint(f);
  u = (u + 0x7FFFu + ((u >> 16) & 1u)) >> 16;   // RNE
  return (unsigned short)u;
}

// ---------------- kernel 1: convert x + 3 W to bf16 ----------------
__global__ void conv_kernel(const float* __restrict__ x, const float* __restrict__ w0,
                            const float* __restrict__ w1, const float* __restrict__ w2,
                            unsigned short* __restrict__ xb, unsigned short* __restrict__ wb0,
                            unsigned short* __restrict__ wb1, unsigned short* __restrict__ wb2) {
  int gid = blockIdx.x * 256 + threadIdx.x;   // one float4 each; 327680 total
  const float* src; unsigned short* dst; int off;
  if (gid < 131072)      { src = x;  dst = xb;  off = gid; }
  else if (gid < 196608) { src = w0; dst = wb0; off = gid - 131072; }
  else if (gid < 262144) { src = w1; dst = wb1; off = gid - 196608; }
  else                   { src = w2; dst = wb2; off = gid - 262144; }
  float4 v = ((const float4*)src)[off];
  ushort4 r;
  r.x = f2bf(v.x); r.y = f2bf(v.y); r.z = f2bf(v.z); r.w = f2bf(v.w);
  ((ushort4*)dst)[off] = r;
}

// ---------------- kernel 2: P = x @ W^T + b (bf16 MFMA, f32 out) ----------------
// grid (16, 8, 3), block 256 (4 waves, 2x2), wave computes 32x32.
__global__ void proj_kernel(const unsigned short* __restrict__ xb,
                            const unsigned short* __restrict__ wb0,
                            const unsigned short* __restrict__ wb1,
                            const unsigned short* __restrict__ wb2,
                            const float* __restrict__ bias0, const float* __restrict__ bias1,
                            const float* __restrict__ bias2,
                            float* __restrict__ P0, float* __restrict__ P1, float* __restrict__ P2) {
  const int mt = blockIdx.x, nt = blockIdx.y, which = blockIdx.z;
  const unsigned short* W = (which == 0) ? wb0 : (which == 1) ? wb1 : wb2;
  const float* bias       = (which == 0) ? bias0 : (which == 1) ? bias1 : bias2;
  float* P                = (which == 0) ? P0 : (which == 1) ? P1 : P2;
  const int tid = threadIdx.x;
  const int wv = tid >> 6, lane = tid & 63;
  const int wm = wv >> 1, wn = wv & 1;
  const int mbase = mt * 64 + wm * 32, nbase = nt * 64 + wn * 32;
  const int lr = lane & 15, lk = lane >> 4;
  // A: lane holds A[row=lane&15][k=(lane>>4)*8+e]; B: B[k][col=lane&15] = W[col][k]
  const bf16x8* A0 = (const bf16x8*)(xb + (size_t)(mbase + lr) * 512 + lk * 8);
  const bf16x8* A1 = (const bf16x8*)(xb + (size_t)(mbase + 16 + lr) * 512 + lk * 8);
  const bf16x8* B0 = (const bf16x8*)(W + (size_t)(nbase + lr) * 512 + lk * 8);
  const bf16x8* B1 = (const bf16x8*)(W + (size_t)(nbase + 16 + lr) * 512 + lk * 8);
  f32x4 acc00 = {0.f, 0.f, 0.f, 0.f}, acc01 = acc00, acc10 = acc00, acc11 = acc00;
  #pragma unroll
  for (int kt = 0; kt < 16; ++kt) {
    bf16x8 a0 = A0[kt * 4], a1 = A1[kt * 4];
    bf16x8 b0 = B0[kt * 4], b1 = B1[kt * 4];
    acc00 = __builtin_amdgcn_mfma_f32_16x16x32_bf16(a0, b0, acc00, 0, 0, 0);
    acc01 = __builtin_amdgcn_mfma_f32_16x16x32_bf16(a0, b1, acc01, 0, 0, 0);
    acc10 = __builtin_amdgcn_mfma_f32_16x16x32_bf16(a1, b0, acc10, 0, 0, 0);
    acc11 = __builtin_amdgcn_mfma_f32_16x16x32_bf16(a1, b1, acc11, 0, 0, 0);
  }
  // C/D: col = lane&15, row = (lane>>4)*4 + v  [guide m89/m91 verified]
  const int r0 = mbase + lk * 4, c0 = nbase + lr;
  #pragma unroll
  for (int v = 0; v < 4; ++v) {
    P[(size_t)(r0 + v) * 512 + c0]           = acc00[v] + bias[c0];
    P[(size_t)(r0 + v) * 512 + c0 + 16]      = acc01[v] + bias[c0 + 16];
    P[(size_t)(r0 + 16 + v) * 512 + c0]      = acc10[v] + bias[c0];
    P[(size_t)(r0 + 16 + v) * 512 + c0 + 16] = acc11[v] + bias[c0 + 16];
  }
}

// ---------------- kernel 3: sa/sb matvecs: sa[b,h,i] = sum_d aff[h,d]*Pfc[b,i,h*32+d] ----
__global__ void aux_kernel(const float* __restrict__ Pfc, const float* __restrict__ Pfc2,
                           const float* __restrict__ aff,
                           float* __restrict__ sa, float* __restrict__ sb) {
  int gid = blockIdx.x * 256 + threadIdx.x;  // 16384
  int h = gid & 15, row = gid >> 4;          // row = b*512 + i
  const float* ar = aff + h * 32;
  const float* p1 = Pfc + (size_t)row * 512 + h * 32;
  const float* p2 = Pfc2 + (size_t)row * 512 + h * 32;
  float s1 = 0.f, s2 = 0.f;
  #pragma unroll
  for (int d = 0; d < 32; ++d) {
    float a = ar[d];
    s1 = fmaf(a, p1[d], s1);
    s2 = fmaf(a, p2[d], s2);
  }
  int b = row >> 9, i = row & 511;
  int o = (b * NH + h) * NN + i;
  sa[o] = s1; sb[o] = s2;
}

// ---------------- kernel 4: attention ----------------
// grid (8 i-tiles, 16 heads, 2 batch), block 512 = 8 waves.
// Wave w: j-chunk [w*64, w*64+64); lane owns row i = it*64+lane.
// Online softmax with defer-max (rescale only on __any(s > m+8)).
// Flash-combine 8 partials in LDS (XOR-swizzled to dodge stride-128B bank conflicts).
__launch_bounds__(512)
__global__ void attn_kernel(const float* __restrict__ Pfc, const float* __restrict__ Pfc2,
                            const float* __restrict__ Pval, const float* __restrict__ sa,
                            const float* __restrict__ sb, const float* __restrict__ aff,
                            const float* __restrict__ adj, float* __restrict__ hpre) {
  const int it = blockIdx.x, h = blockIdx.y, b = blockIdx.z;
  const int tid = threadIdx.x;
  const int w = tid >> 6, lane = tid & 63;
  const int i = it * 64 + lane;

  __shared__ float sm_[8][64];
  __shared__ float sl_[8][64];
  __shared__ float so_[8][2048];   // [wave][i][32] with float4 XOR swizzle

  float a[DD], af[DD], o[DD];
  const float4* Ap = (const float4*)(Pfc + ((size_t)(b * NN + i)) * 512 + h * DD);
  const float4* Fp = (const float4*)(aff + h * DD);
  #pragma unroll
  for (int d4 = 0; d4 < 8; ++d4) {
    float4 av = Ap[d4];
    a[4 * d4 + 0] = av.x; a[4 * d4 + 1] = av.y; a[4 * d4 + 2] = av.z; a[4 * d4 + 3] = av.w;
    float4 fv = Fp[d4];
    af[4 * d4 + 0] = fv.x; af[4 * d4 + 1] = fv.y; af[4 * d4 + 2] = fv.z; af[4 * d4 + 3] = fv.w;
    o[4 * d4 + 0] = 0.f; o[4 * d4 + 1] = 0.f; o[4 * d4 + 2] = 0.f; o[4 * d4 + 3] = 0.f;
  }
  const float sai = sa[(b * NH + h) * NN + i];
  const float* sbp = sb + (b * NH + h) * NN;
  float m = -1e9f, l = 0.f;

  const float* adjp = adj + ((size_t)(b * NN + i)) * NN;
  const int j0 = w * 64;
  for (int jb = j0; jb < j0 + 64; jb += 4) {
    float4 adjv = *(const float4*)(adjp + jb);
    #pragma unroll
    for (int u = 0; u < 4; ++u) {
      const int jj = jb + u;
      // wave-uniform row pointers (b, jj, h uniform) -> scalar-cache friendly
      const float4* Bp = (const float4*)(Pfc2 + ((size_t)(b * NN + jj)) * 512 + h * DD);
      const float4* Vp = (const float4*)(Pval + ((size_t)(b * NN + jj)) * 512 + h * DD);
      float4 bv0 = Bp[0], bv1 = Bp[1], bv2 = Bp[2], bv3 = Bp[3];
      float4 bv4 = Bp[4], bv5 = Bp[5], bv6 = Bp[6], bv7 = Bp[7];
      float4 vv0 = Vp[0], vv1 = Vp[1], vv2 = Vp[2], vv3 = Vp[3];
      float4 vv4 = Vp[4], vv5 = Vp[5], vv6 = Vp[6], vv7 = Vp[7];
      float sbj = sbp[jj];
      float t0 = 0.f, t1 = 0.f, t2 = 0.f, t3 = 0.f;
      #define SCORE4(q, bv)                                           \
        t0 = fmaf(af[4*q+0], fabsf(a[4*q+0] + bv.x), t0);             \
        t1 = fmaf(af[4*q+1], fabsf(a[4*q+1] + bv.y), t1);             \
        t2 = fmaf(af[4*q+2], fabsf(a[4*q+2] + bv.z), t2);             \
        t3 = fmaf(af[4*q+3], fabsf(a[4*q+3] + bv.w), t3);
      SCORE4(0, bv0) SCORE4(1, bv1) SCORE4(2, bv2) SCORE4(3, bv3)
      SCORE4(4, bv4) SCORE4(5, bv5) SCORE4(6, bv6) SCORE4(7, bv7)
      #undef SCORE4
      float adjval = (u == 0) ? adjv.x : (u == 1) ? adjv.y : (u == 2) ? adjv.z : adjv.w;
      float s = 0.6f * (sai + sbj) + 0.4f * ((t0 + t1) + (t2 + t3));
      s = (adjval < 1e-5f) ? -1e9f : s;
      if (__any(s > m + 8.f)) {
        float mn = fmaxf(m, s);
        float sc = __expf(m - mn);
        l *= sc;
        #pragma unroll
        for (int d = 0; d < DD; ++d) o[d] *= sc;
        m = mn;
      }
      float p = __expf(s - m);
      l += p;
      #define PV4(q, vv)                                   \
        o[4*q+0] = fmaf(p, vv.x, o[4*q+0]);                \
        o[4*q+1] = fmaf(p, vv.y, o[4*q+1]);                \
        o[4*q+2] = fmaf(p, vv.z, o[4*q+2]);                \
        o[4*q+3] = fmaf(p, vv.w, o[4*q+3]);
      PV4(0, vv0) PV4(1, vv1) PV4(2, vv2) PV4(3, vv3)
      PV4(4, vv4) PV4(5, vv5) PV4(6, vv6) PV4(7, vv7)
      #undef PV4
    }
  }

  // write partials (XOR swizzle d4 ^= lane&7 to spread banks)
  sm_[w][lane] = m; sl_[w][lane] = l;
  #pragma unroll
  for (int d4 = 0; d4 < 8; ++d4) {
    int d4s = d4 ^ (lane & 7);
    ((float4*)&so_[w][lane * 32])[d4s] =
        make_float4(o[4 * d4 + 0], o[4 * d4 + 1], o[4 * d4 + 2], o[4 * d4 + 3]);
  }
  __syncthreads();

  // combine: thread -> (i2 = tid>>3, dg = tid&7) for coalesced 128B row writes
  const int dg = tid & 7, i2 = tid >> 3;
  float M = sm_[0][i2];
  #pragma unroll
  for (int ww = 1; ww < 8; ++ww) M = fmaxf(M, sm_[ww][i2]);
  float L = 0.f;
  float ox = 0.f, oy = 0.f, oz = 0.f, owv = 0.f;
  #pragma unroll
  for (int ww = 0; ww < 8; ++ww) {
    float f = __expf(sm_[ww][i2] - M);
    L = fmaf(sl_[ww][i2], f, L);
    float4 ov = ((const float4*)&so_[ww][i2 * 32])[dg ^ (i2 & 7)];
    ox = fmaf(f, ov.x, ox); oy = fmaf(f, ov.y, oy);
    oz = fmaf(f, ov.z, oz); owv = fmaf(f, ov.w, owv);
  }
  float inv = 1.f / L;
  size_t idx = ((size_t)(b * NN) + it * 64 + i2) * 512 + h * DD + dg * 4;
  float4 pf = *(const float4*)(Pfc + idx);   // x_aff_flat residual
  float4 res;
  res.x = pf.x + ox * inv; res.y = pf.y + oy * inv;
  res.z = pf.z + oz * inv; res.w = pf.w + owv * inv;
  *(float4*)(hpre + idx) = res;
}

// ---------------- kernel 5: layernorm + relu ----------------
__global__ void ln_kernel(const float* __restrict__ hpre, const float* __restrict__ g,
                          const float* __restrict__ be, float* __restrict__ out) {
  const int row = blockIdx.x, tid = threadIdx.x;   // 256 threads, 2 f32 each
  float2 v = ((const float2*)(hpre + (size_t)row * 512))[tid];
  float s = v.x + v.y, q = v.x * v.x + v.y * v.y;
  #pragma unroll
  for (int off = 32; off > 0; off >>= 1) {
    s += __shfl_xor(s, off);
    q += __shfl_xor(q, off);
  }
  __shared__ float ps[4], pq[4];
  const int w = tid >> 6, lane = tid & 63;
  if (lane == 0) { ps[w] = s; pq[w] = q; }
  __syncthreads();
  s = ps[0] + ps[1] + ps[2] + ps[3];
  q = pq[0] + pq[1] + pq[2] + pq[3];
  float mu = s * (1.f / 512.f);
  float var = q * (1.f / 512.f) - mu * mu;
  float rstd = rsqrtf(var + 1e-5f);
  float2 gv = ((const float2*)g)[tid], bv = ((const float2*)be)[tid];
  float y0 = (v.x - mu) * rstd * gv.x + bv.x;
  float y1 = (v.y - mu) * rstd * gv.y + bv.y;
  ((float2*)out)[(size_t)row * 256 + tid] = make_float2(fmaxf(y0, 0.f), fmaxf(y1, 0.f));
}

extern "C" void kernel_launch(void* const* d_in, const int* in_sizes, int n_in,
                              void* d_out, int out_size, void* d_ws, size_t ws_size,
                              hipStream_t stream) {
  const float* x    = (const float*)d_in[0];
  const float* adj  = (const float*)d_in[1];
  const float* Wfc  = (const float*)d_in[2];
  const float* bfc  = (const float*)d_in[3];
  const float* Wfc2 = (const float*)d_in[4];
  const float* bfc2 = (const float*)d_in[5];
  const float* Wval = (const float*)d_in[6];
  const float* bval = (const float*)d_in[7];
  const float* aff  = (const float*)d_in[8];
  // d_in[9] = aff_bias: uniform per softmax row -> softmax-invariant -> skipped
  const float* lng  = (const float*)d_in[10];
  const float* lnb  = (const float*)d_in[11];
  float* out = (float*)d_out;

  char* ws = (char*)d_ws;
  // region A (0..2.5MB): bf16 staging for proj, then reused as hpre after proj
  unsigned short* xb  = (unsigned short*)(ws);
  unsigned short* wb0 = (unsigned short*)(ws + 1048576);
  unsigned short* wb1 = (unsigned short*)(ws + 1572864);
  unsigned short* wb2 = (unsigned short*)(ws + 2097152);
  float* hpre = (float*)(ws);
  float* Pfc  = (float*)(ws + 2621440);
  float* Pfc2 = (float*)(ws + 4718592);
  float* Pval = (float*)(ws + 6815744);
  float* sa   = (float*)(ws + 8912896);
  float* sb   = (float*)(ws + 8978432);
  // total workspace footprint: 9,043,968 bytes

  conv_kernel<<<1280, 256, 0, stream>>>(x, Wfc, Wfc2, Wval, xb, wb0, wb1, wb2);
  proj_kernel<<<dim3(16, 8, 3), 256, 0, stream>>>(xb, wb0, wb1, wb2, bfc, bfc2, bval,
                                                  Pfc, Pfc2, Pval);
  aux_kernel<<<64, 256, 0, stream>>>(Pfc, Pfc2, aff, sa, sb);
  attn_kernel<<<dim3(8, 16, 2), 512, 0, stream>>>(Pfc, Pfc2, Pval, sa, sb, aff, adj, hpre);
  ln_kernel<<<1024, 256, 0, stream>>>(hpre, lng, lnb, out);
}